// Round 15
// baseline (82.606 us; speedup 1.0000x reference)
//
#include <hip/hip_runtime.h>
#include <cstdint>

#define B_   32
#define CIN  256
#define COUT 256
#define H_   56
#define W_   56
#define HP   58          // padded spatial dim (pad=1 each side)
#define HW   (H_ * W_)   // 3136

typedef int   v4i  __attribute__((ext_vector_type(4)));
typedef int   v8i  __attribute__((ext_vector_type(8)));
typedef float v16f __attribute__((ext_vector_type(16)));

// ==================================================================
// XNOR conv via MX-fp4 MFMA (9099 TOPS = 2.07x i8):
// a,w in {+1,-1} as fp4 e2m1 (+1=0x2, -1=0xA), zero-pad = 0x0 (exact).
// Unity scales (e8m0 127 -> 2^0), scale word 0x7F7F7F7F (opsel-immune).
// Products +-1, |sums| <= 2304: exact in fp32. Verified absmax 0 (r14).
// ==================================================================

// ---- pack_a4: NCHW fp32 -> padded NHWC fp4. A4[b][hh][ww][128B] ----
__global__ __launch_bounds__(256) void pack_a4_kernel(
    const float* __restrict__ x, const float* __restrict__ alpha,
    char* __restrict__ A4) {
  const int w = threadIdx.x & 63;
  const int q = threadIdx.x >> 6;
  const int hh = blockIdx.x * 4 + q;
  const int b = blockIdx.y;
  if (hh >= HP) return;
  char* rowbase = A4 + (size_t)(b * HP + hh) * (HP * 128);
  const uint4 z = make_uint4(0u, 0u, 0u, 0u);
  if (hh == 0 || hh == HP - 1) {           // border row: all zeros
    for (int i = w; i < HP * 8; i += 64) *(uint4*)(rowbase + i * 16) = z;
    return;
  }
  const int h = hh - 1;
  if (w < W_) {
    char* dst = rowbase + (w + 1) * 128;
    const float* xp = x + (size_t)b * CIN * HW + h * W_ + w;
    #pragma unroll
    for (int cw = 0; cw < 8; ++cw) {       // 16B = 32 channels per iter
      uint32_t wd[4];
      #pragma unroll
      for (int u = 0; u < 4; ++u) {
        uint32_t word = 0;
        #pragma unroll
        for (int n = 0; n < 8; ++n) {
          int c = cw * 32 + u * 8 + n;
          float v = xp[(size_t)c * HW];
          word |= ((v > alpha[c]) ? 0x2u : 0xAu) << (n * 4);
        }
        wd[u] = word;
      }
      *(uint4*)(dst + cw * 16) = *(uint4*)wd;
    }
  } else if (w == 56 || w == 57) {         // border pixels ww=0 / ww=57
    char* dst = rowbase + ((w == 56) ? 0 : (HP - 1)) * 128;
    #pragma unroll
    for (int i = 0; i < 8; ++i) *(uint4*)(dst + i * 16) = z;
  }
}

// ---- pack_w4: W in B-fragment form for mfma 32x32x64 fp4 ----
// Wf4[((tap*4 + kc)*8 + ng)*64 + lane] (16B): co = ng*32 + (lane&31),
// k elem j=0..31: ci = kc*64 + (lane>>5)*32 + j; nibble j -> byte j>>1.
__global__ __launch_bounds__(256) void pack_w4_kernel(
    const float* __restrict__ wt, v4i* __restrict__ Wf) {
  int id = blockIdx.x * 256 + threadIdx.x;   // 18432 total
  int lane = id & 63;
  int ng = (id >> 6) & 7;
  int kc = (id >> 9) & 3;
  int tap = id >> 11;
  if (tap >= 9) return;
  int kh = tap / 3, kw = tap - kh * 3;
  int co = ng * 32 + (lane & 31);
  int cib = kc * 64 + (lane >> 5) * 32;
  uint32_t wd[4];
  #pragma unroll
  for (int u = 0; u < 4; ++u) {
    uint32_t word = 0;
    #pragma unroll
    for (int n = 0; n < 8; ++n) {
      int ci = cib + u * 8 + n;
      float v = wt[((size_t)(co * CIN + ci) * 3 + kh) * 3 + kw];
      word |= ((v > 0.0f) ? 0x2u : 0xAu) << (n * 4);
    }
    wd[u] = word;
  }
  Wf[id] = *(v4i*)wd;
}

// ---- conv_mfma v12: fp4, ng=2 per wave (24 MFMAs/batch) ----
// Block: 256 thr / 4 waves = full N256. Tile M128 (4 oh x 32 ow) x N256.
// Wave: M128 x N64 (ng = wn*2, wn*2+1); acc[4 mg][2 ng] v16f = 128 regs.
// Slab [gr8][rr6][ww34] x 16B = 26,112 B, single fill (full 256 ci fp4).
// Batch (kc 0..3, kw 0..2): 6 af b128 reads + 6 bf 16B loads + 24 MFMAs
// -> af/MFMA = 0.25, bf bytes/MFMA = 256 (proven economy), chain gap =
// 8 independent MFMAs (~280cy) between acc[mg][ng] links.
// launch_bounds(256,2): 256-reg cap -> no spill from v8i staging.
__global__ __launch_bounds__(256, 2) void conv_mfma_kernel(
    const char* __restrict__ A4, const v4i* __restrict__ Wf,
    float* __restrict__ out) {
  __shared__ alignas(16) char lds[26112];   // [gr8][rr6][ww34] x 16B
  const int tid = threadIdx.x;
  const int lane = tid & 63;
  const int l31 = lane & 31;
  const int hi  = lane >> 5;
  const int wn  = tid >> 6;

  // bid -> XCD-chunked bijective swizzle (896 = 8*112)
  const int bid = blockIdx.x;
  const int wg  = (bid & 7) * 112 + (bid >> 3);
  const int owc = wg & 1;
  const int rest = wg >> 1;
  const int ohq = rest % 14;
  const int b   = rest / 14;
  const int oh0 = ohq * 4;
  const int owbase = owc * 32;

  // ---- fill slab: linear i = (gr*6+rr)*34 + wwl ----
  {
    const char* srcT = A4 + ((size_t)(b * HP + oh0) * HP + owbase) * 128;
    for (int i = tid; i < 1632; i += 256) {
      int gr  = i / 204;                 // ci granule 0..7 (kc*2+hi)
      int rem = i - gr * 204;
      int rr  = rem / 34;
      int wwl = rem - rr * 34;
      uint4 v = make_uint4(0u, 0u, 0u, 0u);
      if (owbase + wwl < HP)
        v = *(const uint4*)(srcT + ((size_t)rr * HP + wwl) * 128 + gr * 16);
      *(uint4*)(lds + i * 16) = v;
    }
  }
  __syncthreads();

  v16f acc[4][2];
  #pragma unroll
  for (int m = 0; m < 4; ++m)
    #pragma unroll
    for (int n = 0; n < 2; ++n)
      #pragma unroll
      for (int e = 0; e < 16; ++e) acc[m][n][e] = 0.0f;

  // af addr = lds + (kc*2+hi)*3264 + rr*544 + (l31+kw)*16
  const char* abase = lds + hi * 3264 + l31 * 16;
  const v4i* wb = Wf + (wn * 2) * 64 + lane;   // ng0 = 2*wn
  const v4i zero4 = {0, 0, 0, 0};

  #pragma unroll
  for (int kc = 0; kc < 4; ++kc) {
    #pragma unroll
    for (int kw = 0; kw < 3; ++kw) {
      v4i af[6];
      #pragma unroll
      for (int rr = 0; rr < 6; ++rr)
        af[rr] = *(const v4i*)(abase + kc * 6528 + rr * 544 + kw * 16);
      v4i bf[3][2];
      #pragma unroll
      for (int kh = 0; kh < 3; ++kh) {
        bf[kh][0] = wb[((kh * 3 + kw) * 4 + kc) * 512];
        bf[kh][1] = wb[((kh * 3 + kw) * 4 + kc) * 512 + 64];
      }
      #pragma unroll
      for (int kh = 0; kh < 3; ++kh) {
        v8i b80 = __builtin_shufflevector(bf[kh][0], zero4, 0, 1, 2, 3, 4, 5, 6, 7);
        v8i b81 = __builtin_shufflevector(bf[kh][1], zero4, 0, 1, 2, 3, 4, 5, 6, 7);
        #pragma unroll
        for (int mg = 0; mg < 4; ++mg) {
          v8i a8 = __builtin_shufflevector(af[mg + kh], zero4, 0, 1, 2, 3, 4, 5, 6, 7);
          acc[mg][0] = __builtin_amdgcn_mfma_scale_f32_32x32x64_f8f6f4(
              a8, b80, acc[mg][0], 4, 4, 0, 0x7F7F7F7F, 0, 0x7F7F7F7F);
          acc[mg][1] = __builtin_amdgcn_mfma_scale_f32_32x32x64_f8f6f4(
              a8, b81, acc[mg][1], 4, 4, 0, 0x7F7F7F7F, 0, 0x7F7F7F7F);
        }
      }
    }
  }

  // ---- epilogue: per-wave transpose via dead slab, row stores ----
  __syncthreads();                   // slab dead for all waves
  char* scr = lds + wn * 4608;       // [co 32] stride 144B x 32 floats

  #pragma unroll
  for (int ng = 0; ng < 2; ++ng) {
    const int co0 = (wn * 2 + ng) * 32;
    #pragma unroll
    for (int ohl = 0; ohl < 4; ++ohl) {
      #pragma unroll
      for (int q = 0; q < 4; ++q) {
        float4 f;
        f.x = acc[ohl][ng][q * 4 + 0];
        f.y = acc[ohl][ng][q * 4 + 1];
        f.z = acc[ohl][ng][q * 4 + 2];
        f.w = acc[ohl][ng][q * 4 + 3];
        // m = q*8 + hi*4 + j -> byte q*32 + hi*16
        *(float4*)(scr + l31 * 144 + q * 32 + hi * 16) = f;
      }
      asm volatile("s_waitcnt lgkmcnt(0)" ::: "memory");
      __builtin_amdgcn_sched_barrier(0);
      #pragma unroll
      for (int t = 0; t < 4; ++t) {
        int idx = t * 64 + lane;       // 0..255 = co_l*8 + s
        int co_l = idx >> 3;
        int s = idx & 7;
        int ow = owbase + s * 4;
        if (ow + 3 < W_) {             // owc=1 drops s>=6 (garbage cols)
          float4 v = *(const float4*)(scr + co_l * 144 + s * 16);
          float* op = out + ((size_t)(b * COUT + co0 + co_l) * H_ + oh0 + ohl) * W_ + ow;
          *(float4*)op = v;
        }
      }
      asm volatile("s_waitcnt lgkmcnt(0)" ::: "memory");
      __builtin_amdgcn_sched_barrier(0);
    }
  }
}

// ==================================================================
extern "C" void kernel_launch(void* const* d_in, const int* in_sizes, int n_in,
                              void* d_out, int out_size, void* d_ws, size_t ws_size,
                              hipStream_t stream) {
  const float* x     = (const float*)d_in[0];
  const float* alpha = (const float*)d_in[1];
  const float* wt    = (const float*)d_in[2];
  float* out = (float*)d_out;

  const size_t needA = (size_t)B_ * HP * HP * 128;   // 13,778,944 B
  char* A4 = (char*)d_ws;
  v4i* Wf  = (v4i*)(A4 + needA);                     // 294,912 B

  pack_a4_kernel<<<dim3(15, 32), 256, 0, stream>>>(x, alpha, A4);
  pack_w4_kernel<<<72, 256, 0, stream>>>(wt, Wf);
  conv_mfma_kernel<<<dim3(B_ * 14 * 2), 256, 0, stream>>>(A4, Wf, out);
}

// Round 16
// 75.910 us; speedup vs baseline: 1.0882x; 1.0882x over previous
//
#include <hip/hip_runtime.h>
#include <cstdint>

#define B_   32
#define CIN  256
#define COUT 256
#define H_   56
#define W_   56
#define HP   58          // padded spatial dim (pad=1 each side)
#define HW   (H_ * W_)   // 3136

typedef int   v4i  __attribute__((ext_vector_type(4)));
typedef int   v8i  __attribute__((ext_vector_type(8)));
typedef float v16f __attribute__((ext_vector_type(16)));

// ==================================================================
// XNOR conv via MX-fp4 MFMA (9099 TOPS = 2.07x i8):
// a,w in {+1,-1} as fp4 e2m1 (+1=0x2, -1=0xA), zero-pad = 0x0 (exact).
// Unity scales (e8m0 127 -> 2^0), scale word 0x7F7F7F7F (opsel-immune).
// Products +-1, |sums| <= 2304: exact in fp32. Verified absmax 0 (r14).
// ==================================================================

// ---- pack_a4: NCHW fp32 -> padded NHWC fp4. A4[b][hh][ww][128B] ----
__global__ __launch_bounds__(256) void pack_a4_kernel(
    const float* __restrict__ x, const float* __restrict__ alpha,
    char* __restrict__ A4) {
  const int w = threadIdx.x & 63;
  const int q = threadIdx.x >> 6;
  const int hh = blockIdx.x * 4 + q;
  const int b = blockIdx.y;
  if (hh >= HP) return;
  char* rowbase = A4 + (size_t)(b * HP + hh) * (HP * 128);
  const uint4 z = make_uint4(0u, 0u, 0u, 0u);
  if (hh == 0 || hh == HP - 1) {           // border row: all zeros
    for (int i = w; i < HP * 8; i += 64) *(uint4*)(rowbase + i * 16) = z;
    return;
  }
  const int h = hh - 1;
  if (w < W_) {
    char* dst = rowbase + (w + 1) * 128;
    const float* xp = x + (size_t)b * CIN * HW + h * W_ + w;
    #pragma unroll
    for (int cw = 0; cw < 8; ++cw) {       // 16B = 32 channels per iter
      uint32_t wd[4];
      #pragma unroll
      for (int u = 0; u < 4; ++u) {
        uint32_t word = 0;
        #pragma unroll
        for (int n = 0; n < 8; ++n) {
          int c = cw * 32 + u * 8 + n;
          float v = xp[(size_t)c * HW];
          word |= ((v > alpha[c]) ? 0x2u : 0xAu) << (n * 4);
        }
        wd[u] = word;
      }
      *(uint4*)(dst + cw * 16) = *(uint4*)wd;
    }
  } else if (w == 56 || w == 57) {         // border pixels ww=0 / ww=57
    char* dst = rowbase + ((w == 56) ? 0 : (HP - 1)) * 128;
    #pragma unroll
    for (int i = 0; i < 8; ++i) *(uint4*)(dst + i * 16) = z;
  }
}

// ---- pack_w4: W in B-fragment form for mfma 32x32x64 fp4 ----
// Wf4[((tap*4 + kc)*8 + ng)*64 + lane] (16B): co = ng*32 + (lane&31),
// k elem j=0..31: ci = kc*64 + (lane>>5)*32 + j; nibble j -> byte j>>1.
__global__ __launch_bounds__(256) void pack_w4_kernel(
    const float* __restrict__ wt, v4i* __restrict__ Wf) {
  int id = blockIdx.x * 256 + threadIdx.x;   // 18432 total
  int lane = id & 63;
  int ng = (id >> 6) & 7;
  int kc = (id >> 9) & 3;
  int tap = id >> 11;
  if (tap >= 9) return;
  int kh = tap / 3, kw = tap - kh * 3;
  int co = ng * 32 + (lane & 31);
  int cib = kc * 64 + (lane >> 5) * 32;
  uint32_t wd[4];
  #pragma unroll
  for (int u = 0; u < 4; ++u) {
    uint32_t word = 0;
    #pragma unroll
    for (int n = 0; n < 8; ++n) {
      int ci = cib + u * 8 + n;
      float v = wt[((size_t)(co * CIN + ci) * 3 + kh) * 3 + kw];
      word |= ((v > 0.0f) ? 0x2u : 0xAu) << (n * 4);
    }
    wd[u] = word;
  }
  Wf[id] = *(v4i*)wd;
}

// undef-high v8i: fp4 operands (cbsz/blgp=4) read only v[0:3]; leaving
// v[4:7] undef avoids zero-fill movs and ~32 live VGPRs (r15 lesson).
static __device__ __forceinline__ v8i up8(v4i x) {
  return __builtin_shufflevector(x, x, 0, 1, 2, 3, -1, -1, -1, -1);
}

// ---- conv_mfma v13: r14 structure + undef-high staging + 4 blk/CU ----
// Block: 256 thr / 4 waves. Tile M128 (4 oh x 32 ow) x N128 (coh).
// Wave: M128 x N32; acc[4] v16f = 64 regs; est live ~110 -> lb(256,4):
// 4 waves/SIMD = 4 blocks/CU, pacing 4+3 (vs r14's 3+3+1).
// Slab [gr8][rr6][ww34] x 16B = 26,112 B, single fill (256 ci fp4).
// Batch (kc 0..3, kw 0..2): 6 af b128 reads + 3 bf 16B loads + 12 MFMAs.
__global__ __launch_bounds__(256, 4) void conv_mfma_kernel(
    const char* __restrict__ A4, const v4i* __restrict__ Wf,
    float* __restrict__ out) {
  __shared__ alignas(16) char lds[26112];   // [gr8][rr6][ww34] x 16B
  const int tid = threadIdx.x;
  const int lane = tid & 63;
  const int l31 = lane & 31;
  const int hi  = lane >> 5;
  const int wn  = tid >> 6;

  // bid -> XCD-chunked bijective swizzle (1792 = 8*224)
  const int bid = blockIdx.x;
  const int wg  = (bid & 7) * 224 + (bid >> 3);
  const int coh = wg & 1;
  const int owc = (wg >> 1) & 1;
  const int rest = wg >> 2;
  const int ohq = rest % 14;
  const int b   = rest / 14;
  const int oh0 = ohq * 4;
  const int owbase = owc * 32;

  // ---- fill slab: linear i = (gr*6+rr)*34 + wwl ----
  {
    const char* srcT = A4 + ((size_t)(b * HP + oh0) * HP + owbase) * 128;
    for (int i = tid; i < 1632; i += 256) {
      int gr  = i / 204;                 // ci granule 0..7 (kc*2+hi)
      int rem = i - gr * 204;
      int rr  = rem / 34;
      int wwl = rem - rr * 34;
      uint4 v = make_uint4(0u, 0u, 0u, 0u);
      if (owbase + wwl < HP)
        v = *(const uint4*)(srcT + ((size_t)rr * HP + wwl) * 128 + gr * 16);
      *(uint4*)(lds + i * 16) = v;
    }
  }
  __syncthreads();

  v16f acc[4];
  #pragma unroll
  for (int m = 0; m < 4; ++m)
    #pragma unroll
    for (int e = 0; e < 16; ++e) acc[m][e] = 0.0f;

  // af addr = lds + (kc*2+hi)*3264 + rr*544 + (l31+kw)*16
  const char* abase = lds + hi * 3264 + l31 * 16;
  const v4i* wb = Wf + (coh * 4 + wn) * 64 + lane;  // ng = coh*4+wn

  #pragma unroll
  for (int kc = 0; kc < 4; ++kc) {
    #pragma unroll
    for (int kw = 0; kw < 3; ++kw) {
      v4i af[6];
      #pragma unroll
      for (int rr = 0; rr < 6; ++rr)
        af[rr] = *(const v4i*)(abase + kc * 6528 + rr * 544 + kw * 16);
      v4i bf[3];
      #pragma unroll
      for (int kh = 0; kh < 3; ++kh)
        bf[kh] = wb[((kh * 3 + kw) * 4 + kc) * 512];
      #pragma unroll
      for (int kh = 0; kh < 3; ++kh) {
        v8i b8 = up8(bf[kh]);
        #pragma unroll
        for (int ohl = 0; ohl < 4; ++ohl) {
          acc[ohl] = __builtin_amdgcn_mfma_scale_f32_32x32x64_f8f6f4(
              up8(af[ohl + kh]), b8, acc[ohl], 4, 4,   // cbsz=4, blgp=4 (fp4)
              0, 0x7F7F7F7F, 0, 0x7F7F7F7F);           // unity scales
        }
      }
    }
  }

  // ---- epilogue: per-wave transpose via dead slab, row stores ----
  __syncthreads();                   // slab dead for all waves
  char* scr = lds + wn * 4608;       // [co 32] stride 144B x 32 floats
  const int co0 = (coh * 4 + wn) * 32;

  #pragma unroll
  for (int ohl = 0; ohl < 4; ++ohl) {
    #pragma unroll
    for (int q = 0; q < 4; ++q) {
      float4 f;
      f.x = acc[ohl][q * 4 + 0];
      f.y = acc[ohl][q * 4 + 1];
      f.z = acc[ohl][q * 4 + 2];
      f.w = acc[ohl][q * 4 + 3];
      // m = q*8 + hi*4 + j -> byte q*32 + hi*16
      *(float4*)(scr + l31 * 144 + q * 32 + hi * 16) = f;
    }
    asm volatile("s_waitcnt lgkmcnt(0)" ::: "memory");
    __builtin_amdgcn_sched_barrier(0);
    #pragma unroll
    for (int t = 0; t < 4; ++t) {
      int idx = t * 64 + lane;       // 0..255 = co_l*8 + s
      int co_l = idx >> 3;
      int s = idx & 7;
      int ow = owbase + s * 4;
      if (ow + 3 < W_) {             // owc=1 drops s>=6 (garbage cols)
        float4 v = *(const float4*)(scr + co_l * 144 + s * 16);
        float* op = out + ((size_t)(b * COUT + co0 + co_l) * H_ + oh0 + ohl) * W_ + ow;
        *(float4*)op = v;
      }
    }
    asm volatile("s_waitcnt lgkmcnt(0)" ::: "memory");
    __builtin_amdgcn_sched_barrier(0);
  }
}

// ==================================================================
extern "C" void kernel_launch(void* const* d_in, const int* in_sizes, int n_in,
                              void* d_out, int out_size, void* d_ws, size_t ws_size,
                              hipStream_t stream) {
  const float* x     = (const float*)d_in[0];
  const float* alpha = (const float*)d_in[1];
  const float* wt    = (const float*)d_in[2];
  float* out = (float*)d_out;

  const size_t needA = (size_t)B_ * HP * HP * 128;   // 13,778,944 B
  char* A4 = (char*)d_ws;
  v4i* Wf  = (v4i*)(A4 + needA);                     // 294,912 B

  pack_a4_kernel<<<dim3(15, 32), 256, 0, stream>>>(x, alpha, A4);
  pack_w4_kernel<<<72, 256, 0, stream>>>(wt, Wf);
  conv_mfma_kernel<<<dim3(B_ * 14 * 2 * 2), 256, 0, stream>>>(A4, Wf, out);
}

// Round 18
// 72.853 us; speedup vs baseline: 1.1339x; 1.0420x over previous
//
#include <hip/hip_runtime.h>
#include <cstdint>

#define B_   32
#define CIN  256
#define COUT 256
#define H_   56
#define W_   56
#define HP   58          // padded spatial dim (pad=1 each side)
#define HW   (H_ * W_)   // 3136

typedef int   v4i  __attribute__((ext_vector_type(4)));
typedef int   v8i  __attribute__((ext_vector_type(8)));
typedef float v16f __attribute__((ext_vector_type(16)));

// ==================================================================
// XNOR conv via MX-fp4 MFMA (9099 TOPS = 2.07x i8):
// a,w in {+1,-1} as fp4 e2m1 (+1=0x2, -1=0xA), zero-pad = 0x0 (exact).
// Unity scales (e8m0 127 -> 2^0), scale word 0x7F7F7F7F (opsel-immune).
// Products +-1, |sums| <= 2304: exact in fp32. Verified absmax 0 (r14/r16).
// ==================================================================

// ---- fused pack: blocks 0..479 pack A (NCHW fp32 -> padded NHWC fp4),
//      blocks 480..551 pack W into B-fragment form (one launch gap saved).
__global__ __launch_bounds__(256) void pack_kernel(
    const float* __restrict__ x, const float* __restrict__ alpha,
    const float* __restrict__ wt, char* __restrict__ A4,
    v4i* __restrict__ Wf) {
  const int bidx = blockIdx.x;
  if (bidx < 480) {
    // ---------------- pack_a4 ----------------
    const int w = threadIdx.x & 63;
    const int q = threadIdx.x >> 6;
    const int hh = (bidx % 15) * 4 + q;
    const int b = bidx / 15;
    if (hh >= HP) return;
    char* rowbase = A4 + (size_t)(b * HP + hh) * (HP * 128);
    const uint4 z = make_uint4(0u, 0u, 0u, 0u);
    if (hh == 0 || hh == HP - 1) {           // border row: all zeros
      for (int i = w; i < HP * 8; i += 64) *(uint4*)(rowbase + i * 16) = z;
      return;
    }
    const int h = hh - 1;
    if (w < W_) {
      char* dst = rowbase + (w + 1) * 128;
      const float* xp = x + (size_t)b * CIN * HW + h * W_ + w;
      #pragma unroll
      for (int cw = 0; cw < 8; ++cw) {       // 16B = 32 channels per iter
        uint32_t wd[4];
        #pragma unroll
        for (int u = 0; u < 4; ++u) {
          uint32_t word = 0;
          #pragma unroll
          for (int n = 0; n < 8; ++n) {
            int c = cw * 32 + u * 8 + n;
            float v = xp[(size_t)c * HW];
            word |= ((v > alpha[c]) ? 0x2u : 0xAu) << (n * 4);
          }
          wd[u] = word;
        }
        *(uint4*)(dst + cw * 16) = *(uint4*)wd;
      }
    } else if (w == 56 || w == 57) {         // border pixels ww=0 / ww=57
      char* dst = rowbase + ((w == 56) ? 0 : (HP - 1)) * 128;
      #pragma unroll
      for (int i = 0; i < 8; ++i) *(uint4*)(dst + i * 16) = z;
    }
  } else {
    // ---------------- pack_w4 ----------------
    // Wf4[((tap*4 + kc)*8 + ng)*64 + lane]: co = ng*32 + (lane&31),
    // k elem j: ci = kc*64 + (lane>>5)*32 + j; nibble j -> byte j>>1.
    int id = (bidx - 480) * 256 + threadIdx.x;   // 18432 total
    int lane = id & 63;
    int ng = (id >> 6) & 7;
    int kc = (id >> 9) & 3;
    int tap = id >> 11;
    if (tap >= 9) return;
    int kh = tap / 3, kw = tap - kh * 3;
    int co = ng * 32 + (lane & 31);
    int cib = kc * 64 + (lane >> 5) * 32;
    uint32_t wd[4];
    #pragma unroll
    for (int u = 0; u < 4; ++u) {
      uint32_t word = 0;
      #pragma unroll
      for (int n = 0; n < 8; ++n) {
        int ci = cib + u * 8 + n;
        float v = wt[((size_t)(co * CIN + ci) * 3 + kh) * 3 + kw];
        word |= ((v > 0.0f) ? 0x2u : 0xAu) << (n * 4);
      }
      wd[u] = word;
    }
    Wf[id] = *(v4i*)wd;
  }
}

// undef-high v8i: fp4 operands (cbsz/blgp=4) read only v[0:3]; leaving
// v[4:7] undef avoids zero-fill movs and ~32 live VGPRs (r15 lesson).
static __device__ __forceinline__ v8i up8(v4i x) {
  return __builtin_shufflevector(x, x, 0, 1, 2, 3, -1, -1, -1, -1);
}

// ---- conv_mfma (r16-proven): fp4, M128xN128 block, 4 blocks/CU ----
// Block: 256 thr / 4 waves. Tile M128 (4 oh x 32 ow) x N128 (coh).
// Wave: M128 x N32; acc[4] v16f = 64 regs; lb(256,4) -> 4 blocks/CU.
// Slab [gr8][rr6][ww34] x 16B = 26,112 B, single fill (256 ci fp4).
// Batch (kc 0..3, kw 0..2): 6 af b128 reads + 3 bf 16B loads + 12 MFMAs.
// Epilogue: per-ohl stride-144 scr (exactly 32x144 = 4608 B/wave, fits
// in dead slab; r17's pair-drain overflowed its region -> reverted).
__global__ __launch_bounds__(256, 4) void conv_mfma_kernel(
    const char* __restrict__ A4, const v4i* __restrict__ Wf,
    float* __restrict__ out) {
  __shared__ alignas(16) char lds[26112];   // [gr8][rr6][ww34] x 16B
  const int tid = threadIdx.x;
  const int lane = tid & 63;
  const int l31 = lane & 31;
  const int hi  = lane >> 5;
  const int wn  = tid >> 6;

  // bid -> XCD-chunked bijective swizzle (1792 = 8*224)
  const int bid = blockIdx.x;
  const int wg  = (bid & 7) * 224 + (bid >> 3);
  const int coh = wg & 1;
  const int owc = (wg >> 1) & 1;
  const int rest = wg >> 2;
  const int ohq = rest % 14;
  const int b   = rest / 14;
  const int oh0 = ohq * 4;
  const int owbase = owc * 32;

  // ---- fill slab: linear i = (gr*6+rr)*34 + wwl ----
  {
    const char* srcT = A4 + ((size_t)(b * HP + oh0) * HP + owbase) * 128;
    for (int i = tid; i < 1632; i += 256) {
      int gr  = i / 204;                 // ci granule 0..7 (kc*2+hi)
      int rem = i - gr * 204;
      int rr  = rem / 34;
      int wwl = rem - rr * 34;
      uint4 v = make_uint4(0u, 0u, 0u, 0u);
      if (owbase + wwl < HP)
        v = *(const uint4*)(srcT + ((size_t)rr * HP + wwl) * 128 + gr * 16);
      *(uint4*)(lds + i * 16) = v;
    }
  }
  __syncthreads();

  v16f acc[4];
  #pragma unroll
  for (int m = 0; m < 4; ++m)
    #pragma unroll
    for (int e = 0; e < 16; ++e) acc[m][e] = 0.0f;

  // af addr = lds + (kc*2+hi)*3264 + rr*544 + (l31+kw)*16
  const char* abase = lds + hi * 3264 + l31 * 16;
  const v4i* wb = Wf + (coh * 4 + wn) * 64 + lane;  // ng = coh*4+wn

  #pragma unroll
  for (int kc = 0; kc < 4; ++kc) {
    #pragma unroll
    for (int kw = 0; kw < 3; ++kw) {
      v4i af[6];
      #pragma unroll
      for (int rr = 0; rr < 6; ++rr)
        af[rr] = *(const v4i*)(abase + kc * 6528 + rr * 544 + kw * 16);
      v4i bf[3];
      #pragma unroll
      for (int kh = 0; kh < 3; ++kh)
        bf[kh] = wb[((kh * 3 + kw) * 4 + kc) * 512];
      #pragma unroll
      for (int kh = 0; kh < 3; ++kh) {
        v8i b8 = up8(bf[kh]);
        #pragma unroll
        for (int ohl = 0; ohl < 4; ++ohl) {
          acc[ohl] = __builtin_amdgcn_mfma_scale_f32_32x32x64_f8f6f4(
              up8(af[ohl + kh]), b8, acc[ohl], 4, 4,   // cbsz=4, blgp=4 (fp4)
              0, 0x7F7F7F7F, 0, 0x7F7F7F7F);           // unity scales
        }
      }
    }
  }

  // ---- epilogue: per-wave transpose via dead slab, row stores ----
  __syncthreads();                   // slab dead for all waves
  char* scr = lds + wn * 4608;       // [co 32] stride 144B x 32 floats
  const int co0 = (coh * 4 + wn) * 32;

  #pragma unroll
  for (int ohl = 0; ohl < 4; ++ohl) {
    #pragma unroll
    for (int q = 0; q < 4; ++q) {
      float4 f;
      f.x = acc[ohl][q * 4 + 0];
      f.y = acc[ohl][q * 4 + 1];
      f.z = acc[ohl][q * 4 + 2];
      f.w = acc[ohl][q * 4 + 3];
      // m = q*8 + hi*4 + j -> byte q*32 + hi*16
      *(float4*)(scr + l31 * 144 + q * 32 + hi * 16) = f;
    }
    asm volatile("s_waitcnt lgkmcnt(0)" ::: "memory");
    __builtin_amdgcn_sched_barrier(0);
    #pragma unroll
    for (int t = 0; t < 4; ++t) {
      int idx = t * 64 + lane;       // 0..255 = co_l*8 + s
      int co_l = idx >> 3;
      int s = idx & 7;
      int ow = owbase + s * 4;
      if (ow + 3 < W_) {             // owc=1 drops s>=6 (garbage cols)
        float4 v = *(const float4*)(scr + co_l * 144 + s * 16);
        float* op = out + ((size_t)(b * COUT + co0 + co_l) * H_ + oh0 + ohl) * W_ + ow;
        *(float4*)op = v;
      }
    }
    asm volatile("s_waitcnt lgkmcnt(0)" ::: "memory");
    __builtin_amdgcn_sched_barrier(0);
  }
}

// ==================================================================
extern "C" void kernel_launch(void* const* d_in, const int* in_sizes, int n_in,
                              void* d_out, int out_size, void* d_ws, size_t ws_size,
                              hipStream_t stream) {
  const float* x     = (const float*)d_in[0];
  const float* alpha = (const float*)d_in[1];
  const float* wt    = (const float*)d_in[2];
  float* out = (float*)d_out;

  const size_t needA = (size_t)B_ * HP * HP * 128;   // 13,778,944 B
  char* A4 = (char*)d_ws;
  v4i* Wf  = (v4i*)(A4 + needA);                     // 294,912 B

  pack_kernel<<<552, 256, 0, stream>>>(x, alpha, wt, A4, Wf);
  conv_mfma_kernel<<<dim3(B_ * 14 * 2 * 2), 256, 0, stream>>>(A4, Wf, out);
}

// Round 20
// 68.631 us; speedup vs baseline: 1.2036x; 1.0615x over previous
//
#include <hip/hip_runtime.h>
#include <cstdint>

#define B_   32
#define CIN  256
#define COUT 256
#define H_   56
#define W_   56
#define HP   58          // padded spatial dim (pad=1 each side)
#define HW   (H_ * W_)   // 3136

typedef int   v4i  __attribute__((ext_vector_type(4)));
typedef int   v8i  __attribute__((ext_vector_type(8)));
typedef float v16f __attribute__((ext_vector_type(16)));

// ==================================================================
// XNOR conv via MX-fp4 MFMA: a,w in {+1,-1} as fp4 e2m1 (+1=0x2,
// -1=0xA), zero-pad = 0x0 (exact). Unity scales (0x7F7F7F7F).
// Products +-1, |sums| <= 2304: exact in fp32. absmax 0 (r14/r16/r18).
// ==================================================================

// ---- fused pack v2.1: wave-per-(b, granule, 64-pixel chunk).
// 3136 = 49 x 64 -> 12544 waves = 3136 blocks; each thread: 32
// coalesced loads (4 groups of 8), one 16B store.
// blocks 3136..3367: border zeroing (FIXED: r19 used r&463 for r%464 --
// 464 is not a power of two; un-zeroed border granules kept 0xAA poison).
// blocks 3368..3439: pack_w4.
__global__ __launch_bounds__(256, 8) void pack_kernel(
    const float* __restrict__ x, const float* __restrict__ alpha,
    const float* __restrict__ wt, char* __restrict__ A4,
    v4i* __restrict__ Wf) {
  const int bidx = blockIdx.x;
  const int tid = threadIdx.x;
  if (bidx < 3136) {
    // ---------------- pack_a4 main (interior pixels) ----------------
    const int lane = tid & 63;
    const int gw = bidx * 4 + (tid >> 6);    // global wave 0..12543
    const int chunk = gw % 49;
    const int g = (gw / 49) & 7;             // ci granule (32 channels)
    const int b = gw / (49 * 8);
    const int pix = chunk * 64 + lane;       // 0..3135
    const int h = pix / 56;
    const int w = pix - h * 56;

    const float* xp = x + ((size_t)(b * CIN + g * 32) * HW + pix);
    uint32_t wd[4];
    #pragma unroll
    for (int u = 0; u < 4; ++u) {            // 8 channels -> one u32
      uint32_t word = 0;
      #pragma unroll
      for (int n = 0; n < 8; ++n) {
        int c = u * 8 + n;
        float v = xp[(size_t)c * HW];
        word |= ((v > alpha[g * 32 + c]) ? 0x2u : 0xAu) << (n * 4);
      }
      wd[u] = word;
    }
    char* dst = A4 + ((size_t)(b * HP + h + 1) * HP + (w + 1)) * 128 + g * 16;
    *(uint4*)dst = *(uint4*)wd;
  } else if (bidx < 3368) {
    // ---------------- border zeroing ----------------
    // rows hh in {0,57} (58 ww x 8 g) + cols ww in {0,57} (58 hh x 8 g)
    // per b: 928 + 928 = 1856 granules; corners overlap (both 0).
    int t = (bidx - 3136) * 256 + tid;       // 0..59391
    if (t >= 32 * 1856) return;
    int b = t / 1856;
    int r = t - b * 1856;
    int hh, ww, idx;
    if (r < 928) {
      hh = (r < 464) ? 0 : (HP - 1);
      idx = (r < 464) ? r : r - 464;         // r % 464 (explicit)
      ww = idx >> 3;
    } else {
      int r2 = r - 928;
      ww = (r2 < 464) ? 0 : (HP - 1);
      idx = (r2 < 464) ? r2 : r2 - 464;      // r2 % 464 (explicit)
      hh = idx >> 3;
    }
    int g = idx & 7;
    char* dst = A4 + ((size_t)(b * HP + hh) * HP + ww) * 128 + g * 16;
    *(uint4*)dst = make_uint4(0u, 0u, 0u, 0u);
  } else {
    // ---------------- pack_w4 ----------------
    // Wf4[((tap*4 + kc)*8 + ng)*64 + lane]: co = ng*32 + (lane&31),
    // k elem j: ci = kc*64 + (lane>>5)*32 + j; nibble j -> byte j>>1.
    int id = (bidx - 3368) * 256 + tid;      // 18432 total
    int lane = id & 63;
    int ng = (id >> 6) & 7;
    int kc = (id >> 9) & 3;
    int tap = id >> 11;
    if (tap >= 9) return;
    int kh = tap / 3, kw = tap - kh * 3;
    int co = ng * 32 + (lane & 31);
    int cib = kc * 64 + (lane >> 5) * 32;
    uint32_t wd[4];
    #pragma unroll
    for (int u = 0; u < 4; ++u) {
      uint32_t word = 0;
      #pragma unroll
      for (int n = 0; n < 8; ++n) {
        int ci = cib + u * 8 + n;
        float v = wt[((size_t)(co * CIN + ci) * 3 + kh) * 3 + kw];
        word |= ((v > 0.0f) ? 0x2u : 0xAu) << (n * 4);
      }
      wd[u] = word;
    }
    Wf[id] = *(v4i*)wd;
  }
}

// undef-high v8i: fp4 operands (cbsz/blgp=4) read only v[0:3]; leaving
// v[4:7] undef avoids zero-fill movs and ~32 live VGPRs (r15 lesson).
static __device__ __forceinline__ v8i up8(v4i x) {
  return __builtin_shufflevector(x, x, 0, 1, 2, 3, -1, -1, -1, -1);
}

// ---- conv_mfma (r18-proven, byte-identical): near its MFMA floor ----
__global__ __launch_bounds__(256, 4) void conv_mfma_kernel(
    const char* __restrict__ A4, const v4i* __restrict__ Wf,
    float* __restrict__ out) {
  __shared__ alignas(16) char lds[26112];   // [gr8][rr6][ww34] x 16B
  const int tid = threadIdx.x;
  const int lane = tid & 63;
  const int l31 = lane & 31;
  const int hi  = lane >> 5;
  const int wn  = tid >> 6;

  // bid -> XCD-chunked bijective swizzle (1792 = 8*224)
  const int bid = blockIdx.x;
  const int wg  = (bid & 7) * 224 + (bid >> 3);
  const int coh = wg & 1;
  const int owc = (wg >> 1) & 1;
  const int rest = wg >> 2;
  const int ohq = rest % 14;
  const int b   = rest / 14;
  const int oh0 = ohq * 4;
  const int owbase = owc * 32;

  // ---- fill slab: linear i = (gr*6+rr)*34 + wwl ----
  {
    const char* srcT = A4 + ((size_t)(b * HP + oh0) * HP + owbase) * 128;
    for (int i = tid; i < 1632; i += 256) {
      int gr  = i / 204;                 // ci granule 0..7 (kc*2+hi)
      int rem = i - gr * 204;
      int rr  = rem / 34;
      int wwl = rem - rr * 34;
      uint4 v = make_uint4(0u, 0u, 0u, 0u);
      if (owbase + wwl < HP)
        v = *(const uint4*)(srcT + ((size_t)rr * HP + wwl) * 128 + gr * 16);
      *(uint4*)(lds + i * 16) = v;
    }
  }
  __syncthreads();

  v16f acc[4];
  #pragma unroll
  for (int m = 0; m < 4; ++m)
    #pragma unroll
    for (int e = 0; e < 16; ++e) acc[m][e] = 0.0f;

  // af addr = lds + (kc*2+hi)*3264 + rr*544 + (l31+kw)*16
  const char* abase = lds + hi * 3264 + l31 * 16;
  const v4i* wb = Wf + (coh * 4 + wn) * 64 + lane;  // ng = coh*4+wn

  #pragma unroll
  for (int kc = 0; kc < 4; ++kc) {
    #pragma unroll
    for (int kw = 0; kw < 3; ++kw) {
      v4i af[6];
      #pragma unroll
      for (int rr = 0; rr < 6; ++rr)
        af[rr] = *(const v4i*)(abase + kc * 6528 + rr * 544 + kw * 16);
      v4i bf[3];
      #pragma unroll
      for (int kh = 0; kh < 3; ++kh)
        bf[kh] = wb[((kh * 3 + kw) * 4 + kc) * 512];
      #pragma unroll
      for (int kh = 0; kh < 3; ++kh) {
        v8i b8 = up8(bf[kh]);
        #pragma unroll
        for (int ohl = 0; ohl < 4; ++ohl) {
          acc[ohl] = __builtin_amdgcn_mfma_scale_f32_32x32x64_f8f6f4(
              up8(af[ohl + kh]), b8, acc[ohl], 4, 4,   // cbsz=4, blgp=4 (fp4)
              0, 0x7F7F7F7F, 0, 0x7F7F7F7F);           // unity scales
        }
      }
    }
  }

  // ---- epilogue: per-wave transpose via dead slab, row stores ----
  __syncthreads();                   // slab dead for all waves
  char* scr = lds + wn * 4608;       // [co 32] stride 144B x 32 floats
  const int co0 = (coh * 4 + wn) * 32;

  #pragma unroll
  for (int ohl = 0; ohl < 4; ++ohl) {
    #pragma unroll
    for (int q = 0; q < 4; ++q) {
      float4 f;
      f.x = acc[ohl][q * 4 + 0];
      f.y = acc[ohl][q * 4 + 1];
      f.z = acc[ohl][q * 4 + 2];
      f.w = acc[ohl][q * 4 + 3];
      // m = q*8 + hi*4 + j -> byte q*32 + hi*16
      *(float4*)(scr + l31 * 144 + q * 32 + hi * 16) = f;
    }
    asm volatile("s_waitcnt lgkmcnt(0)" ::: "memory");
    __builtin_amdgcn_sched_barrier(0);
    #pragma unroll
    for (int t = 0; t < 4; ++t) {
      int idx = t * 64 + lane;       // 0..255 = co_l*8 + s
      int co_l = idx >> 3;
      int s = idx & 7;
      int ow = owbase + s * 4;
      if (ow + 3 < W_) {             // owc=1 drops s>=6 (garbage cols)
        float4 v = *(const float4*)(scr + co_l * 144 + s * 16);
        float* op = out + ((size_t)(b * COUT + co0 + co_l) * H_ + oh0 + ohl) * W_ + ow;
        *(float4*)op = v;
      }
    }
    asm volatile("s_waitcnt lgkmcnt(0)" ::: "memory");
    __builtin_amdgcn_sched_barrier(0);
  }
}

// ==================================================================
extern "C" void kernel_launch(void* const* d_in, const int* in_sizes, int n_in,
                              void* d_out, int out_size, void* d_ws, size_t ws_size,
                              hipStream_t stream) {
  const float* x     = (const float*)d_in[0];
  const float* alpha = (const float*)d_in[1];
  const float* wt    = (const float*)d_in[2];
  float* out = (float*)d_out;

  const size_t needA = (size_t)B_ * HP * HP * 128;   // 13,778,944 B
  char* A4 = (char*)d_ws;
  v4i* Wf  = (v4i*)(A4 + needA);                     // 294,912 B

  pack_kernel<<<3440, 256, 0, stream>>>(x, alpha, wt, A4, Wf);
  conv_mfma_kernel<<<dim3(B_ * 14 * 2 * 2), 256, 0, stream>>>(A4, Wf, out);
}

// Round 21
// 63.978 us; speedup vs baseline: 1.2912x; 1.0727x over previous
//
#include <hip/hip_runtime.h>
#include <cstdint>

#define B_   32
#define CIN  256
#define COUT 256
#define H_   56
#define W_   56
#define HP   58          // padded spatial dim (pad=1 each side)
#define HW   (H_ * W_)   // 3136

typedef int   v4i  __attribute__((ext_vector_type(4)));
typedef int   v8i  __attribute__((ext_vector_type(8)));
typedef float v16f __attribute__((ext_vector_type(16)));

// ==================================================================
// XNOR conv via MX-fp4 MFMA: a,w in {+1,-1} as fp4 e2m1 (+1=0x2,
// -1=0xA), zero-pad = 0x0 (exact). Unity scales (0x7F7F7F7F).
// Products +-1, |sums| <= 2304: exact in fp32. absmax 0 (r14-r20).
// ==================================================================

// ---- fused pack v3: LDS-staged transpose for full-line writes.
// r20 post-mortem: per-lane 16B stores at 128B stride -> partial-line
// HBM writes (r18 counters: WRITE 39.5MB vs 14.1 ideal, 2.8x RMW).
// New: block = (b, 32-px chunk) x 8 granules. Thread (px=t&31, g=t>>5):
// 32 coalesced plane loads -> 16B -> LDS (XOR swz) -> barrier ->
// re-read as (px=t>>3, slot=t&7) -> 8 threads/pixel = full 128B line,
// wave writes 1KB contiguous. Reads coalesced AND writes full-line.
// blocks 3136..3367: border zeroing. blocks 3368..3439: pack_w4.
__global__ __launch_bounds__(256, 8) void pack_kernel(
    const float* __restrict__ x, const float* __restrict__ alpha,
    const float* __restrict__ wt, char* __restrict__ A4,
    v4i* __restrict__ Wf) {
  __shared__ alignas(16) char sm[4096];
  const int bidx = blockIdx.x;
  const int tid = threadIdx.x;
  if (bidx < 3136) {
    // ---------------- pack_a4 main (interior pixels) ----------------
    const int b = bidx / 98;
    const int chunk = bidx - b * 98;       // 98 chunks of 32 px = 3136
    const int pixbase = chunk * 32;
    const int pxl = tid & 31;
    const int g = tid >> 5;                // ci granule 0..7
    const int pix = pixbase + pxl;

    const float* xp = x + ((size_t)(b * CIN + g * 32) * HW + pix);
    uint32_t wd[4];
    #pragma unroll
    for (int u = 0; u < 4; ++u) {          // 8 channels -> one u32
      uint32_t word = 0;
      #pragma unroll
      for (int n = 0; n < 8; ++n) {
        int c = u * 8 + n;
        float v = xp[(size_t)c * HW];
        word |= ((v > alpha[g * 32 + c]) ? 0x2u : 0xAu) << (n * 4);
      }
      wd[u] = word;
    }
    *(uint4*)(sm + pxl * 128 + ((g ^ (pxl & 7)) << 4)) = *(uint4*)wd;
    __syncthreads();
    const int px2 = tid >> 3;              // 0..31
    const int slot = tid & 7;
    uint4 v = *(const uint4*)(sm + px2 * 128 + ((slot ^ (px2 & 7)) << 4));
    const int gpix = pixbase + px2;
    const int h = gpix / 56;
    const int w = gpix - h * 56;
    char* dst = A4 + ((size_t)(b * HP + h + 1) * HP + (w + 1)) * 128 + slot * 16;
    *(uint4*)dst = v;
  } else if (bidx < 3368) {
    // ---------------- border zeroing (r20-verified) ----------------
    int t = (bidx - 3136) * 256 + tid;     // 0..59391
    if (t >= 32 * 1856) return;
    int b = t / 1856;
    int r = t - b * 1856;
    int hh, ww, idx;
    if (r < 928) {
      hh = (r < 464) ? 0 : (HP - 1);
      idx = (r < 464) ? r : r - 464;       // r % 464 (explicit)
      ww = idx >> 3;
    } else {
      int r2 = r - 928;
      ww = (r2 < 464) ? 0 : (HP - 1);
      idx = (r2 < 464) ? r2 : r2 - 464;    // r2 % 464 (explicit)
      hh = idx >> 3;
    }
    int g = idx & 7;
    char* dst = A4 + ((size_t)(b * HP + hh) * HP + ww) * 128 + g * 16;
    *(uint4*)dst = make_uint4(0u, 0u, 0u, 0u);
  } else {
    // ---------------- pack_w4 (r20-verified) ----------------
    int id = (bidx - 3368) * 256 + tid;    // 18432 total
    int lane = id & 63;
    int ng = (id >> 6) & 7;
    int kc = (id >> 9) & 3;
    int tap = id >> 11;
    if (tap >= 9) return;
    int kh = tap / 3, kw = tap - kh * 3;
    int co = ng * 32 + (lane & 31);
    int cib = kc * 64 + (lane >> 5) * 32;
    uint32_t wd[4];
    #pragma unroll
    for (int u = 0; u < 4; ++u) {
      uint32_t word = 0;
      #pragma unroll
      for (int n = 0; n < 8; ++n) {
        int ci = cib + u * 8 + n;
        float v = wt[((size_t)(co * CIN + ci) * 3 + kh) * 3 + kw];
        word |= ((v > 0.0f) ? 0x2u : 0xAu) << (n * 4);
      }
      wd[u] = word;
    }
    Wf[id] = *(v4i*)wd;
  }
}

// undef-high v8i: fp4 operands (cbsz/blgp=4) read only v[0:3]; leaving
// v[4:7] undef avoids zero-fill movs and ~32 live VGPRs (r15 lesson).
static __device__ __forceinline__ v8i up8(v4i x) {
  return __builtin_shufflevector(x, x, 0, 1, 2, 3, -1, -1, -1, -1);
}

// ---- conv_mfma (r18/r20-proven, byte-identical): at its MFMA floor ----
__global__ __launch_bounds__(256, 4) void conv_mfma_kernel(
    const char* __restrict__ A4, const v4i* __restrict__ Wf,
    float* __restrict__ out) {
  __shared__ alignas(16) char lds[26112];   // [gr8][rr6][ww34] x 16B
  const int tid = threadIdx.x;
  const int lane = tid & 63;
  const int l31 = lane & 31;
  const int hi  = lane >> 5;
  const int wn  = tid >> 6;

  // bid -> XCD-chunked bijective swizzle (1792 = 8*224)
  const int bid = blockIdx.x;
  const int wg  = (bid & 7) * 224 + (bid >> 3);
  const int coh = wg & 1;
  const int owc = (wg >> 1) & 1;
  const int rest = wg >> 2;
  const int ohq = rest % 14;
  const int b   = rest / 14;
  const int oh0 = ohq * 4;
  const int owbase = owc * 32;

  // ---- fill slab: linear i = (gr*6+rr)*34 + wwl ----
  {
    const char* srcT = A4 + ((size_t)(b * HP + oh0) * HP + owbase) * 128;
    for (int i = tid; i < 1632; i += 256) {
      int gr  = i / 204;                 // ci granule 0..7 (kc*2+hi)
      int rem = i - gr * 204;
      int rr  = rem / 34;
      int wwl = rem - rr * 34;
      uint4 v = make_uint4(0u, 0u, 0u, 0u);
      if (owbase + wwl < HP)
        v = *(const uint4*)(srcT + ((size_t)rr * HP + wwl) * 128 + gr * 16);
      *(uint4*)(lds + i * 16) = v;
    }
  }
  __syncthreads();

  v16f acc[4];
  #pragma unroll
  for (int m = 0; m < 4; ++m)
    #pragma unroll
    for (int e = 0; e < 16; ++e) acc[m][e] = 0.0f;

  // af addr = lds + (kc*2+hi)*3264 + rr*544 + (l31+kw)*16
  const char* abase = lds + hi * 3264 + l31 * 16;
  const v4i* wb = Wf + (coh * 4 + wn) * 64 + lane;  // ng = coh*4+wn

  #pragma unroll
  for (int kc = 0; kc < 4; ++kc) {
    #pragma unroll
    for (int kw = 0; kw < 3; ++kw) {
      v4i af[6];
      #pragma unroll
      for (int rr = 0; rr < 6; ++rr)
        af[rr] = *(const v4i*)(abase + kc * 6528 + rr * 544 + kw * 16);
      v4i bf[3];
      #pragma unroll
      for (int kh = 0; kh < 3; ++kh)
        bf[kh] = wb[((kh * 3 + kw) * 4 + kc) * 512];
      #pragma unroll
      for (int kh = 0; kh < 3; ++kh) {
        v8i b8 = up8(bf[kh]);
        #pragma unroll
        for (int ohl = 0; ohl < 4; ++ohl) {
          acc[ohl] = __builtin_amdgcn_mfma_scale_f32_32x32x64_f8f6f4(
              up8(af[ohl + kh]), b8, acc[ohl], 4, 4,   // cbsz=4, blgp=4 (fp4)
              0, 0x7F7F7F7F, 0, 0x7F7F7F7F);           // unity scales
        }
      }
    }
  }

  // ---- epilogue: per-wave transpose via dead slab, row stores ----
  __syncthreads();                   // slab dead for all waves
  char* scr = lds + wn * 4608;       // [co 32] stride 144B x 32 floats
  const int co0 = (coh * 4 + wn) * 32;

  #pragma unroll
  for (int ohl = 0; ohl < 4; ++ohl) {
    #pragma unroll
    for (int q = 0; q < 4; ++q) {
      float4 f;
      f.x = acc[ohl][q * 4 + 0];
      f.y = acc[ohl][q * 4 + 1];
      f.z = acc[ohl][q * 4 + 2];
      f.w = acc[ohl][q * 4 + 3];
      // m = q*8 + hi*4 + j -> byte q*32 + hi*16
      *(float4*)(scr + l31 * 144 + q * 32 + hi * 16) = f;
    }
    asm volatile("s_waitcnt lgkmcnt(0)" ::: "memory");
    __builtin_amdgcn_sched_barrier(0);
    #pragma unroll
    for (int t = 0; t < 4; ++t) {
      int idx = t * 64 + lane;       // 0..255 = co_l*8 + s
      int co_l = idx >> 3;
      int s = idx & 7;
      int ow = owbase + s * 4;
      if (ow + 3 < W_) {             // owc=1 drops s>=6 (garbage cols)
        float4 v = *(const float4*)(scr + co_l * 144 + s * 16);
        float* op = out + ((size_t)(b * COUT + co0 + co_l) * H_ + oh0 + ohl) * W_ + ow;
        *(float4*)op = v;
      }
    }
    asm volatile("s_waitcnt lgkmcnt(0)" ::: "memory");
    __builtin_amdgcn_sched_barrier(0);
  }
}

// ==================================================================
extern "C" void kernel_launch(void* const* d_in, const int* in_sizes, int n_in,
                              void* d_out, int out_size, void* d_ws, size_t ws_size,
                              hipStream_t stream) {
  const float* x     = (const float*)d_in[0];
  const float* alpha = (const float*)d_in[1];
  const float* wt    = (const float*)d_in[2];
  float* out = (float*)d_out;

  const size_t needA = (size_t)B_ * HP * HP * 128;   // 13,778,944 B
  char* A4 = (char*)d_ws;
  v4i* Wf  = (v4i*)(A4 + needA);                     // 294,912 B

  pack_kernel<<<3440, 256, 0, stream>>>(x, alpha, wt, A4, Wf);
  conv_mfma_kernel<<<dim3(B_ * 14 * 2 * 2), 256, 0, stream>>>(A4, Wf, out);
}